// Round 3
// baseline (259.887 us; speedup 1.0000x reference)
//
#include <hip/hip_runtime.h>
#include <hip/hip_cooperative_groups.h>

namespace cg = cooperative_groups;

#define HH 96
#define WW 96
#define OH 90
#define OW 90
#define NPATCH 8100
#define DD 147
#define NPROJ 256
#define TN 64         // patches per virtual block in phase A (M-tile)
#define KPAD 160      // K padded to 5*32 for MFMA
#define NKS 5         // K-steps of 32
#define SORT_T 512
#define NBUCK 4096
#define KPT 16        // keys per thread in rank phase
#define PGRP 16       // reduce: projections per virtual block
#define NCH 64        // reduce: row chunks
#define KPB2 128      // reduce: rows per chunk
#define QSCALE 21.25f // u8 quant: 255/12, range +-6 sigma, zero at 128
#define GRID_B 256    // cooperative grid: 1 block/CU

typedef short bf16x8 __attribute__((ext_vector_type(8)));
typedef float f32x4 __attribute__((ext_vector_type(4)));

__device__ __forceinline__ unsigned short bf16_rne(float f) {
    unsigned u = __builtin_bit_cast(unsigned, f);
    u += 0x7FFFu + ((u >> 16) & 1u);
    return (unsigned short)(u >> 16);
}
__device__ __forceinline__ float bf16_f(unsigned short h) {
    return __builtin_bit_cast(float, (unsigned)h << 16);
}

// v_sad_u8: byte-wise |a-b| sum of 4 lanes + 32-bit accumulate, 1 VALU op.
__device__ __forceinline__ unsigned sad4(unsigned x, unsigned y, unsigned a) {
    unsigned d;
    asm("v_sad_u8 %0, %1, %2, %3" : "=v"(d) : "v"(x), "v"(y), "v"(a));
    return d;
}

// LDS union across phases: max member = phase-B 65,568 B -> 1 block/CU.
union SmemU {
    struct { unsigned short sh[2][TN * KPAD]; } a;                       // 40,960 B
    struct { unsigned hist[NBUCK]; unsigned cnt[NBUCK];
             float skey[8192]; unsigned wsum[8]; } b;                    // 65,568 B
    struct { unsigned short sp[2][PGRP * KPB2]; float sred[2][4]; } c;   //  8,224 B
};

// ---------------------------------------------------------------------------
// Fused cooperative kernel (v11): phases 0/A/B/C separated by grid.sync().
// Eliminates 2 kernel-dispatch overheads (the ~20us unexplained gap in the
// R2 accounting) and dedups the rnd->split-bf16 conversion (phase 0, once,
// vs 254x in-register in R2). Phase math is bit-identical to R2.
// ---------------------------------------------------------------------------
__global__ __launch_bounds__(512, 2)
void fused_swd(const float* __restrict__ x, const float* __restrict__ y,
               const float* __restrict__ rnd,
               unsigned short* __restrict__ rth, unsigned short* __restrict__ rtl,
               int* __restrict__ xm8, int* __restrict__ ym8,
               int* __restrict__ xt8, int* __restrict__ yt8,
               float* __restrict__ pxT, float* __restrict__ pyT,
               unsigned short* __restrict__ rx, unsigned short* __restrict__ iy,
               float* __restrict__ out)
{
    __shared__ SmemU smem;
    cg::grid_group grid = cg::this_grid();
    const int b = blockIdx.x;
    const int tid = threadIdx.x;
    const int wv = tid >> 6, lane = tid & 63;
    const int cl = lane & 15, qk = lane >> 4;

    // ===== Phase 0: rnd [147][256] f32 -> rth/rtl [256][160] bf16 hi/lo ====
    {
        const int idx = b * 512 + tid;          // 0..131071, need 40960
        if (idx < NPROJ * KPAD) {
            const int p = idx / KPAD;
            const int k = idx - p * KPAD;
            const float v = (k < DD) ? rnd[k * NPROJ + p] : 0.f;
            const unsigned short hi = bf16_rne(v);
            rth[idx] = hi;
            rtl[idx] = bf16_rne(v - bf16_f(hi));
        }
        if (b == 0 && tid == 0) out[0] = 0.0f;
    }
    grid.sync();

    // ===== Phase A: patch stage (LDS MFMA A-frags + u8 copies) + proj GEMM ==
    if (b < 254) {
        const int img = b & 1;
        const int n0 = (b >> 1) * TN;
        const float* __restrict__ src = img ? y : x;
        int* __restrict__ m8 = img ? ym8 : xm8;
        int* __restrict__ t8 = img ? yt8 : xt8;
        float* __restrict__ pT = img ? pyT : pxT;

        // B-operand fragments: wave wv -> proj cols 32wv..32wv+31.
        bf16x8 bh[NKS][2], bl[NKS][2];
#pragma unroll
        for (int ks = 0; ks < NKS; ++ks) {
#pragma unroll
            for (int nt = 0; nt < 2; ++nt) {
                const int col = wv * 32 + nt * 16 + cl;
                const int k0 = ks * 32 + qk * 8;
                bh[ks][nt] = *(const bf16x8*)&rth[col * KPAD + k0];
                bl[ks][nt] = *(const bf16x8*)&rtl[col * KPAD + k0];
            }
        }

        // fused staging: unit (t,u) = 4 dims d0=4u..4u+3 of patch n0+t.
        // LDS frag pos: mt=t>>4, r=t&15, ks=d>>5, q=(d&31)>>3, j=d&7
        //   -> (((mt*NKS+ks)*4+q)*16+r)*8 + j
        for (int idx = tid; idx < TN * 40; idx += 512) {
            const int t = idx / 40;
            const int u = idx - t * 40;
            const int n = n0 + t;
            const int d0 = 4 * u;
            unsigned short h4[4], l4[4];
#pragma unroll
            for (int e = 0; e < 4; ++e) {
                const int d = d0 + e;
                float v = 0.f;
                if (n < NPATCH && d < DD) {
                    const int oy = n / OW, ox = n - oy * OW;
                    const int c  = d / 49, r  = d - c * 49;
                    const int di = r / 7,  dj = r - di * 7;
                    v = src[c * (HH * WW) + (oy + di) * WW + (ox + dj)];
                }
                const unsigned short hi = bf16_rne(v);
                h4[e] = hi;
                l4[e] = bf16_rne(v - bf16_f(hi));
            }
            const int mt = t >> 4, r16 = t & 15;
            const int ks = d0 >> 5, q = (d0 & 31) >> 3, jb = d0 & 7;
            const int fidx = (((mt * NKS + ks) * 4 + q) * 16 + r16) * 8 + jb;
            ushort4 hv; hv.x = h4[0]; hv.y = h4[1]; hv.z = h4[2]; hv.w = h4[3];
            ushort4 lv; lv.x = l4[0]; lv.y = l4[1]; lv.z = l4[2]; lv.w = l4[3];
            *(ushort4*)&smem.a.sh[0][fidx] = hv;
            *(ushort4*)&smem.a.sh[1][fidx] = lv;
            if (n < NPATCH) {
                unsigned w = 0;
#pragma unroll
                for (int e = 0; e < 4; ++e) {
                    float f = fmaf(bf16_f(h4[e]), QSCALE, 128.5f);
                    f = fminf(fmaxf(f, 0.f), 255.f);
                    w |= ((unsigned)f) << (8 * e);
                }
                if (u < 32) m8[(size_t)n * 32 + u] = (int)w;
                else        t8[(size_t)n * 8 + (u - 32)] = (int)w;
            }
        }
        __syncthreads();

        // projection GEMM: split-bf16 MFMA (hi*hi + hi*lo + lo*hi).
        f32x4 acc[4][2];
#pragma unroll
        for (int mt = 0; mt < 4; ++mt)
#pragma unroll
            for (int nt = 0; nt < 2; ++nt)
                acc[mt][nt] = (f32x4){0.f, 0.f, 0.f, 0.f};

#pragma unroll
        for (int ks = 0; ks < NKS; ++ks) {
#pragma unroll
            for (int mt = 0; mt < 4; ++mt) {
                const int base = ((mt * NKS + ks) * 64 + lane) * 8;
                const bf16x8 ah = *(const bf16x8*)&smem.a.sh[0][base];
                const bf16x8 al = *(const bf16x8*)&smem.a.sh[1][base];
#pragma unroll
                for (int nt = 0; nt < 2; ++nt) {
                    acc[mt][nt] = __builtin_amdgcn_mfma_f32_16x16x32_bf16(ah, bh[ks][nt], acc[mt][nt], 0, 0, 0);
                    acc[mt][nt] = __builtin_amdgcn_mfma_f32_16x16x32_bf16(ah, bl[ks][nt], acc[mt][nt], 0, 0, 0);
                    acc[mt][nt] = __builtin_amdgcn_mfma_f32_16x16x32_bf16(al, bh[ks][nt], acc[mt][nt], 0, 0, 0);
                }
            }
        }

        // write pT: D col = lane&15 (proj), row = qk*4 + reg (patch).
#pragma unroll
        for (int mt = 0; mt < 4; ++mt) {
            const int patch = n0 + mt * 16 + qk * 4;
#pragma unroll
            for (int nt = 0; nt < 2; ++nt) {
                const int proj = wv * 32 + nt * 16 + cl;
                float* rowp = pT + (size_t)proj * NPATCH + patch;
                if (patch + 3 < NPATCH) {
                    *(f32x4*)rowp = acc[mt][nt];
                } else {
#pragma unroll
                    for (int e = 0; e < 4; ++e)
                        if (patch + e < NPATCH) rowp[e] = acc[mt][nt][e];
                }
            }
        }
    }
    grid.sync();

    // ===== Phase B: bucket-rank, 512 columns as 2 reps of 256 blocks =======
    for (int rep = 0; rep < 2; ++rep) {
        const int pb = b + rep * GRID_B;        // 0..511
        const float* col = pxT + (size_t)pb * NPATCH;  // pxT|pyT adjacent

        {
            uint4 z = make_uint4(0, 0, 0, 0);
            ((uint4*)smem.b.hist)[tid] = z;
            ((uint4*)smem.b.hist)[tid + SORT_T] = z;
        }
        __syncthreads();

        float k[KPT];
        int bk[KPT];
#pragma unroll
        for (int t = 0; t < KPT; ++t) {
            const int i = tid + SORT_T * t;
            if (i < NPATCH) {
                const float v = col[i];
                k[t] = v;
                int bq = (int)((v + 51.2f) * 40.0f);
                bq = bq < 0 ? 0 : (bq > NBUCK - 1 ? NBUCK - 1 : bq);
                bk[t] = bq;
                atomicAdd(&smem.b.hist[bq], 1u);
            } else {
                k[t] = 0.f;
                bk[t] = -1;
            }
        }
        __syncthreads();

        {
            const int b0 = tid * 8;
            unsigned h[8];
#pragma unroll
            for (int q = 0; q < 8; ++q) h[q] = smem.b.hist[b0 + q];
            unsigned tsum = 0;
#pragma unroll
            for (int q = 0; q < 8; ++q) tsum += h[q];
            unsigned acc = tsum;
#pragma unroll
            for (int d = 1; d < 64; d <<= 1) {
                const unsigned v = __shfl_up(acc, d, 64);
                if (lane >= d) acc += v;
            }
            const unsigned wexcl = acc - tsum;
            if (lane == 63) smem.b.wsum[tid >> 6] = acc;
            __syncthreads();
            if (tid == 0) {
                unsigned roff = 0;
#pragma unroll
                for (int w = 0; w < 8; ++w) {
                    const unsigned tt = smem.b.wsum[w];
                    smem.b.wsum[w] = roff;
                    roff += tt;
                }
            }
            __syncthreads();
            unsigned run = smem.b.wsum[tid >> 6] + wexcl;
#pragma unroll
            for (int q = 0; q < 8; ++q) { smem.b.cnt[b0 + q] = run; run += h[q]; }
        }
        __syncthreads();

#pragma unroll
        for (int t = 0; t < KPT; ++t) {
            if (bk[t] >= 0) {
                const unsigned pos = atomicAdd(&smem.b.cnt[bk[t]], 1u);
                smem.b.skey[pos] = k[t];
            }
        }
        __syncthreads();

#pragma unroll
        for (int t = 0; t < KPT; ++t) {
            const int i = tid + SORT_T * t;
            if (bk[t] < 0) continue;
            const int bq = bk[t];
            const unsigned end = smem.b.cnt[bq];
            const unsigned cb = smem.b.hist[bq];
            const unsigned start = end - cb;
            const float myk = k[t];
            unsigned r = start;
            for (unsigned s2 = start; s2 < end; ++s2)
                r += (smem.b.skey[s2] < myk) ? 1u : 0u;
            if (pb < NPROJ)
                rx[(size_t)pb * NPATCH + i] = (unsigned short)r;
            else
                iy[(size_t)(pb - NPROJ) * NPATCH + r] = (unsigned short)i;
        }
        __syncthreads();   // protect hist/cnt/skey re-init for next rep
    }
    grid.sync();

    // ===== Phase C: SAD reduce, 1024 virtual 256-thr blocks = 2 halves x 2 =
    {
        const uint4* __restrict__ xm = (const uint4*)xm8;
        const uint4* __restrict__ ym = (const uint4*)ym8;
        const uint4* __restrict__ xt = (const uint4*)xt8;
        const uint4* __restrict__ yt = (const uint4*)yt8;
        const int half = tid >> 8;
        const int t2 = tid & 255;
        const int wave = t2 >> 6, ln = t2 & 63;
        unsigned short* sp = smem.c.sp[half];

        for (int rep = 0; rep < 2; ++rep) {
            const int vb = ((b << 1) | half) + (rep << 9);   // 0..1023
            const int i0 = (vb & 63) * KPB2;
            const int p0 = (vb >> 6) * PGRP;
            const int iend = min(i0 + KPB2, NPATCH);

            for (int idx = t2; idx < PGRP * KPB2; idx += 256) {
                const int pp = idx >> 7, r = idx & 127;
                int src = i0 + r;
                src = src < NPATCH ? src : NPATCH - 1;
                const int p = p0 + pp;
                const unsigned short rk = rx[(size_t)p * NPATCH + src];
                const unsigned short j = iy[(size_t)p * NPATCH + rk];
                sp[idx] = j < NPATCH ? j : (unsigned short)(NPATCH - 1);
            }
            __syncthreads();

            unsigned uacc = 0;

            // main pass: d = 0..127
            {
                const int g = ln >> 3;
                const int u = ln & 7;
#pragma unroll
                for (int it = 0; it < 4; ++it) {
                    const int i = i0 + wave * 8 + it * 32;
                    const uint4 xa = xm[(size_t)i * 8 + ln];   // OOB -> ym8, masked
                    int jj[PGRP];
#pragma unroll
                    for (int pp = 0; pp < PGRP; ++pp)
                        jj[pp] = sp[pp * KPB2 + (i - i0) + g];
                    uint4 ya[PGRP];
#pragma unroll
                    for (int pp = 0; pp < PGRP; ++pp)
                        ya[pp] = ym[(size_t)jj[pp] * 8 + u];
                    unsigned s0 = 0, s1 = 0;
#pragma unroll
                    for (int pp = 0; pp < PGRP; ++pp) {
                        s0 = sad4(xa.x, ya[pp].x, s0);
                        s1 = sad4(xa.y, ya[pp].y, s1);
                        s0 = sad4(xa.z, ya[pp].z, s0);
                        s1 = sad4(xa.w, ya[pp].w, s1);
                    }
                    uacc += (i + g < iend) ? (s0 + s1) : 0u;
                }
            }

            // tail pass: d = 128..159 (pad quant(0)=128 both sides -> 0)
            {
                const int g2 = ln >> 1;
                const int u2 = ln & 1;
                const int i2 = i0 + wave * 32;
                const uint4 xa = xt[(size_t)i2 * 2 + ln];      // OOB -> yt8, masked
                int jj[PGRP];
#pragma unroll
                for (int pp = 0; pp < PGRP; ++pp)
                    jj[pp] = sp[pp * KPB2 + (i2 - i0) + g2];
                uint4 ya[PGRP];
#pragma unroll
                for (int pp = 0; pp < PGRP; ++pp)
                    ya[pp] = yt[(size_t)jj[pp] * 2 + u2];
                unsigned s0 = 0, s1 = 0;
#pragma unroll
                for (int pp = 0; pp < PGRP; ++pp) {
                    s0 = sad4(xa.x, ya[pp].x, s0);
                    s1 = sad4(xa.y, ya[pp].y, s1);
                    s0 = sad4(xa.z, ya[pp].z, s0);
                    s1 = sad4(xa.w, ya[pp].w, s1);
                }
                uacc += (i2 + g2 < iend) ? (s0 + s1) : 0u;
            }

            float facc = (float)uacc;
#pragma unroll
            for (int o = 32; o > 0; o >>= 1) facc += __shfl_down(facc, o, 64);

            if (ln == 0) smem.c.sred[half][wave] = facc;
            __syncthreads();
            if (t2 == 0) {
                const float s = smem.c.sred[half][0] + smem.c.sred[half][1] +
                                smem.c.sred[half][2] + smem.c.sred[half][3];
                const float scale = (float)(1.0 / ((double)NPROJ * (double)NPATCH *
                                                   (double)DD * (double)QSCALE));
                atomicAdd(out, s * scale);
            }
            __syncthreads();   // protect sp/sred for next rep
        }
    }
}

// ---------------------------------------------------------------------------
extern "C" void kernel_launch(void* const* d_in, const int* in_sizes, int n_in,
                              void* d_out, int out_size, void* d_ws, size_t ws_size,
                              hipStream_t stream)
{
    const float* x   = (const float*)d_in[0];
    const float* y   = (const float*)d_in[1];
    const float* rnd = (const float*)d_in[2];

    char* ws = (char*)d_ws;
    // workspace layout (16B-aligned; xm8|ym8 and xt8|yt8 adjacent so masked
    // OOB reads in phase C stay in-bounds; pxT|pyT adjacent for phase B):
    int* xm8 = (int*)(ws + 0);          // 8100*128 = 1,036,800
    int* ym8 = (int*)(ws + 1036800);    // 1,036,800
    int* xt8 = (int*)(ws + 2073600);    // 8100*32  =   259,200
    int* yt8 = (int*)(ws + 2332800);    //               259,200
    float* pxT = (float*)(ws + 2592000);     // 256*8100*4 = 8,294,400
    float* pyT = (float*)(ws + 10886400);    //             8,294,400
    unsigned short* rx = (unsigned short*)(ws + 19180800);  // 4,147,200
    unsigned short* iy = (unsigned short*)(ws + 23328000);  // 4,147,200
    unsigned short* rth = (unsigned short*)(ws + 27475200); // 256*160*2 = 81,920
    unsigned short* rtl = (unsigned short*)(ws + 27557120); //             81,920
    // high-water: 27,639,040 bytes
    float* out = (float*)d_out;

    void* args[] = {
        (void*)&x, (void*)&y, (void*)&rnd,
        (void*)&rth, (void*)&rtl,
        (void*)&xm8, (void*)&ym8, (void*)&xt8, (void*)&yt8,
        (void*)&pxT, (void*)&pyT,
        (void*)&rx, (void*)&iy,
        (void*)&out
    };
    hipLaunchCooperativeKernel((const void*)fused_swd, dim3(GRID_B), dim3(512),
                               args, 0, stream);
}

// Round 4
// 120.073 us; speedup vs baseline: 2.1644x; 2.1644x over previous
//
#include <hip/hip_runtime.h>

#define HH 96
#define WW 96
#define OH 90
#define OW 90
#define NPATCH 8100
#define DD 147
#define NPROJ 256
#define TN 64         // patches per block in kernel A (M-tile)
#define KPAD 160      // K padded to 5*32 for MFMA
#define NKS 5         // K-steps of 32
#define SORT_T 1024   // rank kernel threads (16 waves)
#define NBUCK 4096
#define KPT 8         // keys per thread in rank kernel (1024 thr x 8 = 8192)
#define PGRP 16       // reduce: projections per block
#define NCH 64        // reduce: row chunks (grid.x)
#define KPB2 128      // reduce: rows per chunk
#define QSCALE 21.25f // u8 quant: 255/12, range +-6 sigma, zero at 128

typedef short bf16x8 __attribute__((ext_vector_type(8)));
typedef float f32x4 __attribute__((ext_vector_type(4)));

__device__ __forceinline__ unsigned short bf16_rne(float f) {
    unsigned u = __builtin_bit_cast(unsigned, f);
    u += 0x7FFFu + ((u >> 16) & 1u);
    return (unsigned short)(u >> 16);
}
__device__ __forceinline__ float bf16_f(unsigned short h) {
    return __builtin_bit_cast(float, (unsigned)h << 16);
}

// v_sad_u8: byte-wise |a-b| sum of 4 lanes + 32-bit accumulate, 1 VALU op.
__device__ __forceinline__ unsigned sad4(unsigned x, unsigned y, unsigned a) {
    unsigned d;
    asm("v_sad_u8 %0, %1, %2, %3" : "=v"(d) : "v"(x), "v"(y), "v"(a));
    return d;
}

// ---------------------------------------------------------------------------
// Kernel A (v7, reverted to R2 = proven): each wave builds its 20 B-operand
// fragments (hi/lo split-bf16 of rnd, 80 VGPR) directly in registers; the
// conversion loads overlap the patch-gather staging. One staging pass per
// thread-unit: 4 dims of one patch -> LDS hi/lo MFMA A-fragments + u8 gather
// copy (linear quant for kernel C's v_sad_u8).
// Projection GEMM = split-bf16 MFMA (hi*hi + hi*lo + lo*hi), f32 accumulate.
// grid (127,2) ~= 1 block/CU, launch_bounds(512,2) -> 256 VGPR cap.
// D layout (m89-verified): col = lane&15, row = (lane>>4)*4 + reg.
// ---------------------------------------------------------------------------
__global__ __launch_bounds__(512, 2)
void patch_proj_kernel(const float* __restrict__ x, const float* __restrict__ y,
                       const float* __restrict__ rnd,
                       int* __restrict__ xm8, int* __restrict__ ym8,
                       int* __restrict__ xt8, int* __restrict__ yt8,
                       float* __restrict__ pxT, float* __restrict__ pyT,
                       float* __restrict__ out)
{
    __shared__ unsigned short sh[2][TN * KPAD];   // hi, lo planes: 40960 B
    const int tid = threadIdx.x;
    const int n0 = blockIdx.x * TN;
    const int img = blockIdx.y;
    const float* __restrict__ src = img ? y : x;
    int* __restrict__ m8 = img ? ym8 : xm8;
    int* __restrict__ t8 = img ? yt8 : xt8;
    float* __restrict__ pT = img ? pyT : pxT;
    if (blockIdx.x == 0 && img == 0 && tid == 0) out[0] = 0.0f;

    const int wv = tid >> 6, lane = tid & 63;
    const int cl = lane & 15, qk = lane >> 4;

    // ---- B-operand fragments in registers (wave wv -> proj cols 32wv..+31).
    bf16x8 bh[NKS][2], bl[NKS][2];
#pragma unroll
    for (int ks = 0; ks < NKS; ++ks) {
#pragma unroll
        for (int nt = 0; nt < 2; ++nt) {
            const int col = wv * 32 + nt * 16 + cl;
#pragma unroll
            for (int j = 0; j < 8; ++j) {
                const int k = ks * 32 + qk * 8 + j;
                const float v = (k < DD) ? rnd[k * NPROJ + col] : 0.f;
                const unsigned short h = bf16_rne(v);
                bh[ks][nt][j] = (short)h;
                bl[ks][nt][j] = (short)bf16_rne(v - bf16_f(h));
            }
        }
    }

    // ---- fused staging: unit (t, u) = 4 dims d0=4u..4u+3 of patch n0+t.
    // LDS frag pos: mt=t>>4, r=t&15, ks=d>>5, q=(d&31)>>3, j=d&7
    //   -> (((mt*NKS+ks)*4+q)*16+r)*8 + j ; d0%4==0 keeps 4 elems contiguous.
    for (int idx = tid; idx < TN * 40; idx += 512) {
        const int t = idx / 40;
        const int u = idx - t * 40;
        const int n = n0 + t;
        const int d0 = 4 * u;
        unsigned short h4[4], l4[4];
#pragma unroll
        for (int e = 0; e < 4; ++e) {
            const int d = d0 + e;
            float v = 0.f;
            if (n < NPATCH && d < DD) {
                const int oy = n / OW, ox = n - oy * OW;
                const int c  = d / 49, r  = d - c * 49;
                const int di = r / 7,  dj = r - di * 7;
                v = src[c * (HH * WW) + (oy + di) * WW + (ox + dj)];
            }
            const unsigned short hi = bf16_rne(v);
            h4[e] = hi;
            l4[e] = bf16_rne(v - bf16_f(hi));
        }
        const int mt = t >> 4, r16 = t & 15;
        const int ks = d0 >> 5, q = (d0 & 31) >> 3, jb = d0 & 7;  // jb in {0,4}
        const int fidx = (((mt * NKS + ks) * 4 + q) * 16 + r16) * 8 + jb;
        ushort4 hv; hv.x = h4[0]; hv.y = h4[1]; hv.z = h4[2]; hv.w = h4[3];
        ushort4 lv; lv.x = l4[0]; lv.y = l4[1]; lv.z = l4[2]; lv.w = l4[3];
        *(ushort4*)&sh[0][fidx] = hv;
        *(ushort4*)&sh[1][fidx] = lv;
        if (n < NPATCH) {
            unsigned w = 0;
#pragma unroll
            for (int e = 0; e < 4; ++e) {
                float f = fmaf(bf16_f(h4[e]), QSCALE, 128.5f);
                f = fminf(fmaxf(f, 0.f), 255.f);
                w |= ((unsigned)f) << (8 * e);
            }
            if (u < 32) m8[(size_t)n * 32 + u] = (int)w;
            else        t8[(size_t)n * 8 + (u - 32)] = (int)w;
        }
    }
    __syncthreads();

    // ---- projection GEMM ----
    f32x4 acc[4][2];
#pragma unroll
    for (int mt = 0; mt < 4; ++mt)
#pragma unroll
        for (int nt = 0; nt < 2; ++nt)
            acc[mt][nt] = (f32x4){0.f, 0.f, 0.f, 0.f};

#pragma unroll
    for (int ks = 0; ks < NKS; ++ks) {
#pragma unroll
        for (int mt = 0; mt < 4; ++mt) {
            const int base = ((mt * NKS + ks) * 64 + lane) * 8;
            const bf16x8 ah = *(const bf16x8*)&sh[0][base];
            const bf16x8 al = *(const bf16x8*)&sh[1][base];
#pragma unroll
            for (int nt = 0; nt < 2; ++nt) {
                acc[mt][nt] = __builtin_amdgcn_mfma_f32_16x16x32_bf16(ah, bh[ks][nt], acc[mt][nt], 0, 0, 0);
                acc[mt][nt] = __builtin_amdgcn_mfma_f32_16x16x32_bf16(ah, bl[ks][nt], acc[mt][nt], 0, 0, 0);
                acc[mt][nt] = __builtin_amdgcn_mfma_f32_16x16x32_bf16(al, bh[ks][nt], acc[mt][nt], 0, 0, 0);
            }
        }
    }

    // ---- write pT: D col = lane&15 (proj), row = qk*4 + reg (patch) ----
#pragma unroll
    for (int mt = 0; mt < 4; ++mt) {
        const int patch = n0 + mt * 16 + qk * 4;
#pragma unroll
        for (int nt = 0; nt < 2; ++nt) {
            const int proj = wv * 32 + nt * 16 + cl;
            float* rowp = pT + (size_t)proj * NPATCH + patch;
            if (patch + 3 < NPATCH) {
                *(f32x4*)rowp = acc[mt][nt];
            } else {
#pragma unroll
                for (int e = 0; e < 4; ++e)
                    if (patch + e < NPATCH) rowp[e] = acc[mt][nt][e];
            }
        }
    }
}

// ---------------------------------------------------------------------------
// Kernel B (v11): PAIRED bucket-rank. One block per projection p, 1024 thr
// (16 waves/CU = same TLP as R2's 2x512). Pass 1: x-column -> ranks kept in
// REGISTERS (xr[8]). Pass 2: y-column -> iy built in LDS. Then emit fused
// partner[p][i] = iy_lds[xr[i]] with coalesced u16 stores. Eliminates the
// rx/iy global round-trip (8.3 MB + 2M random scattered stores) and kernel
// C's dependent double-gather staging. Rank math identical to R2 (affine
// buckets, hist->scan->scatter->count-smaller; tie poison 0xFFFF clamped).
// ---------------------------------------------------------------------------
__global__ __launch_bounds__(SORT_T, 4)
void rank_kernel(const float* __restrict__ pT,
                 unsigned short* __restrict__ partner)
{
    __shared__ unsigned hist[NBUCK];            // 16 KB
    __shared__ unsigned cnt[NBUCK];             // 16 KB
    __shared__ float    skey[8192];             // 32 KB
    __shared__ unsigned short iyl[8192];        // 16 KB
    __shared__ unsigned wsum[16];
    const int p = blockIdx.x;
    const int tid = threadIdx.x;
    const int lane = tid & 63;
    const int wid = tid >> 6;

    unsigned short xr[KPT];    // x-ranks of this thread's keys

#pragma unroll
    for (int pass = 0; pass < 2; ++pass) {
        // pass 0: x column p ; pass 1: y column p (pxT|pyT adjacent)
        const float* col = pT + (size_t)(p + pass * NPROJ) * NPATCH;

        ((uint4*)hist)[tid] = make_uint4(0, 0, 0, 0);
        ((uint4*)cnt)[tid]  = make_uint4(0, 0, 0, 0);
        if (pass == 1) {   // init iy poison (tie-collapsed ranks stay 0xFFFF)
            ((uint4*)iyl)[tid] = make_uint4(0xFFFFFFFFu, 0xFFFFFFFFu,
                                            0xFFFFFFFFu, 0xFFFFFFFFu);
            if (tid < 1024) ((uint4*)iyl)[tid + 1024] = make_uint4(
                0xFFFFFFFFu, 0xFFFFFFFFu, 0xFFFFFFFFu, 0xFFFFFFFFu);
        }
        __syncthreads();

        float k[KPT];
        int bk[KPT];
#pragma unroll
        for (int t = 0; t < KPT; ++t) {
            const int i = tid + SORT_T * t;
            if (i < NPATCH) {
                const float v = col[i];
                k[t] = v;
                int b = (int)((v + 51.2f) * 40.0f);
                b = b < 0 ? 0 : (b > NBUCK - 1 ? NBUCK - 1 : b);
                bk[t] = b;
                atomicAdd(&hist[b], 1u);
            } else {
                k[t] = 0.f;
                bk[t] = -1;
            }
        }
        __syncthreads();

        {
            const int b0 = tid * 4;
            unsigned h[4];
#pragma unroll
            for (int q = 0; q < 4; ++q) h[q] = hist[b0 + q];
            unsigned tsum = h[0] + h[1] + h[2] + h[3];
            unsigned acc = tsum;
#pragma unroll
            for (int d = 1; d < 64; d <<= 1) {
                const unsigned v = __shfl_up(acc, d, 64);
                if (lane >= d) acc += v;
            }
            const unsigned wexcl = acc - tsum;
            if (lane == 63) wsum[wid] = acc;
            __syncthreads();
            if (tid == 0) {
                unsigned roff = 0;
#pragma unroll
                for (int w = 0; w < 16; ++w) {
                    const unsigned tt = wsum[w];
                    wsum[w] = roff;
                    roff += tt;
                }
            }
            __syncthreads();
            unsigned run = wsum[wid] + wexcl;
#pragma unroll
            for (int q = 0; q < 4; ++q) { cnt[b0 + q] = run; run += h[q]; }
        }
        __syncthreads();

#pragma unroll
        for (int t = 0; t < KPT; ++t) {
            if (bk[t] >= 0) {
                const unsigned pos = atomicAdd(&cnt[bk[t]], 1u);
                skey[pos] = k[t];
            }
        }
        __syncthreads();

#pragma unroll
        for (int t = 0; t < KPT; ++t) {
            if (bk[t] < 0) continue;
            const int b = bk[t];
            const unsigned end = cnt[b];
            const unsigned cb = hist[b];
            const unsigned start = end - cb;
            const float myk = k[t];
            unsigned r = start;
            for (unsigned s2 = start; s2 < end; ++s2)
                r += (skey[s2] < myk) ? 1u : 0u;
            if (pass == 0) {
                xr[t] = (unsigned short)r;          // keep x-rank in register
            } else {
                iyl[r] = (unsigned short)(tid + SORT_T * t);  // iy[rank] = i
            }
        }
        __syncthreads();   // pass 0: protect hist/cnt/skey re-init; pass 1: iyl done
    }

    // ---- emit fused partner: partner[p][i] = clamp(iy[xr[i]]) ----
#pragma unroll
    for (int t = 0; t < KPT; ++t) {
        const int i = tid + SORT_T * t;
        if (i >= NPATCH) continue;
        const unsigned short j = iyl[xr[t]];
        partner[(size_t)p * NPATCH + i] =
            (j < NPATCH) ? j : (unsigned short)(NPATCH - 1);
    }
}

// ---------------------------------------------------------------------------
// Kernel C (v11): SAD reduce; staging reads the fused partner array with ONE
// coalesced load per element (was rx gather + dependent random iy gather).
// L1 via v_sad_u8 on linear-u8 rows: 1 VALU op per 4 element-pairs.
// ---------------------------------------------------------------------------
__global__ __launch_bounds__(256, 4)
void reduce_kernel(const uint4* __restrict__ xm8, const uint4* __restrict__ ym8,
                   const uint4* __restrict__ xt8, const uint4* __restrict__ yt8,
                   const unsigned short* __restrict__ partner,
                   float* __restrict__ out)
{
    __shared__ unsigned short sp[PGRP * KPB2];
    const int p0 = blockIdx.y * PGRP;
    const int i0 = blockIdx.x * KPB2;
    const int iend = min(i0 + KPB2, NPATCH);
    const int tid = threadIdx.x;
    const int wave = tid >> 6, lane = tid & 63;

    for (int idx = tid; idx < PGRP * KPB2; idx += 256) {
        const int pp = idx >> 7, r = idx & 127;
        int src = i0 + r;
        src = src < NPATCH ? src : NPATCH - 1;
        sp[idx] = partner[(size_t)(p0 + pp) * NPATCH + src];
    }
    __syncthreads();

    unsigned uacc = 0;   // max: 1280 elems * 255 = 326K << 2^32

    // ---- main pass: d = 0..127 ----
    {
        const int g = lane >> 3;
        const int u = lane & 7;
#pragma unroll
        for (int it = 0; it < 4; ++it) {
            const int i = i0 + wave * 8 + it * 32;
            const uint4 xa = xm8[(size_t)i * 8 + lane];   // OOB -> ym8, masked
            int jj[PGRP];
#pragma unroll
            for (int pp = 0; pp < PGRP; ++pp)
                jj[pp] = sp[pp * KPB2 + (i - i0) + g];
            uint4 ya[PGRP];
#pragma unroll
            for (int pp = 0; pp < PGRP; ++pp)
                ya[pp] = ym8[(size_t)jj[pp] * 8 + u];
            unsigned s0 = 0, s1 = 0;
#pragma unroll
            for (int pp = 0; pp < PGRP; ++pp) {
                s0 = sad4(xa.x, ya[pp].x, s0);
                s1 = sad4(xa.y, ya[pp].y, s1);
                s0 = sad4(xa.z, ya[pp].z, s0);
                s1 = sad4(xa.w, ya[pp].w, s1);
            }
            uacc += (i + g < iend) ? (s0 + s1) : 0u;
        }
    }

    // ---- tail pass: d = 128..159 (pad bytes quant(0)=128 both sides -> 0) ----
    {
        const int g2 = lane >> 1;
        const int u2 = lane & 1;
        const int i2 = i0 + wave * 32;
        const uint4 xa = xt8[(size_t)i2 * 2 + lane];      // OOB -> yt8, masked
        int jj[PGRP];
#pragma unroll
        for (int pp = 0; pp < PGRP; ++pp)
            jj[pp] = sp[pp * KPB2 + (i2 - i0) + g2];
        uint4 ya[PGRP];
#pragma unroll
        for (int pp = 0; pp < PGRP; ++pp)
            ya[pp] = yt8[(size_t)jj[pp] * 2 + u2];
        unsigned s0 = 0, s1 = 0;
#pragma unroll
        for (int pp = 0; pp < PGRP; ++pp) {
            s0 = sad4(xa.x, ya[pp].x, s0);
            s1 = sad4(xa.y, ya[pp].y, s1);
            s0 = sad4(xa.z, ya[pp].z, s0);
            s1 = sad4(xa.w, ya[pp].w, s1);
        }
        uacc += (i2 + g2 < iend) ? (s0 + s1) : 0u;
    }

    float facc = (float)uacc;
#pragma unroll
    for (int o = 32; o > 0; o >>= 1) facc += __shfl_down(facc, o, 64);

    __shared__ float sred[4];
    if (lane == 0) sred[wave] = facc;
    __syncthreads();
    if (tid == 0) {
        const float s = sred[0] + sred[1] + sred[2] + sred[3];
        const float scale = (float)(1.0 / ((double)NPROJ * (double)NPATCH *
                                           (double)DD * (double)QSCALE));
        atomicAdd(out, s * scale);
    }
}

// ---------------------------------------------------------------------------
extern "C" void kernel_launch(void* const* d_in, const int* in_sizes, int n_in,
                              void* d_out, int out_size, void* d_ws, size_t ws_size,
                              hipStream_t stream)
{
    const float* x   = (const float*)d_in[0];
    const float* y   = (const float*)d_in[1];
    const float* rnd = (const float*)d_in[2];

    char* ws = (char*)d_ws;
    // workspace layout (16B-aligned; xm8|ym8 and xt8|yt8 adjacent so masked
    // OOB reads in kernel C stay in-bounds; pxT|pyT adjacent for rank kernel):
    int* xm8 = (int*)(ws + 0);          // 8100*128 = 1,036,800
    int* ym8 = (int*)(ws + 1036800);    // 1,036,800
    int* xt8 = (int*)(ws + 2073600);    // 8100*32  =   259,200
    int* yt8 = (int*)(ws + 2332800);    //               259,200
    float* pxT = (float*)(ws + 2592000);     // 256*8100*4 = 8,294,400
    float* pyT = (float*)(ws + 10886400);    //             8,294,400
    unsigned short* partner = (unsigned short*)(ws + 19180800);  // 4,147,200
    // high-water: 23,328,000 bytes
    float* out = (float*)d_out;

    hipLaunchKernelGGL(patch_proj_kernel, dim3((NPATCH + TN - 1) / TN, 2), dim3(512), 0, stream,
                       x, y, rnd, xm8, ym8, xt8, yt8, pxT, pyT, out);
    hipLaunchKernelGGL(rank_kernel, dim3(NPROJ), dim3(SORT_T), 0, stream,
                       pxT, partner);
    hipLaunchKernelGGL(reduce_kernel, dim3(NCH, NPROJ / PGRP), dim3(256), 0, stream,
                       (const uint4*)xm8, (const uint4*)ym8,
                       (const uint4*)xt8, (const uint4*)yt8, partner, out);
}